// Round 3
// baseline (259.859 us; speedup 1.0000x reference)
//
#include <hip/hip_runtime.h>

// Decay-based linear recurrent scan:  S_t = d*S_{t-1} + (1-d)*kv_t ; out_t = q_t*S_t
// fp32, (T,B,H,V,D) = (128,16,8,25,64). 204800 independent channels = 800 waves.
//
// Round-5 design: single pass (minimum traffic, no workspace, one launch) with an
// 8-deep software pipeline in PLAIN C++ loads, pinned by sched_barrier(0).
//   - v4 (same idea, no pinning): compiler collapsed the pipeline (VGPR_Count=44,
//     ~2 loads in flight -> 2.0 TB/s, latency-bound at 7% occupancy).
//   - v5 (inline-asm loads + hand vmcnt): core dump — compiler's waitcnt pass
//     cannot see asm vm-ops; abandoned per rule #18/#19.
//   - v6 (this): loads stay visible to the compiler (its vmcnt insertion is
//     correct by construction); __builtin_amdgcn_sched_barrier(0) after each
//     pipeline step stops the MachineScheduler from sinking prefetches into
//     their uses. Full 128-step unroll => all buffer indices compile-time
//     (rule #20: no scratch). Depth 8 pairs = 16 KB/wave in flight;
//     3.1 waves/CU * 16 KB = 50 KB/CU >> ~10 KB needed for 6.3 TB/s.
//   - Harness fillBuffer does 6.8 TB/s at 9% occupancy => TLP is sufficient;
//     MLP per wave was the deficit.
//   - out stores non-temporal: keeps q/kv LLC-resident (round-0 counters show
//     LLC absorbing ~105 MB/iter of re-reads; don't evict them with out).

#define T_DIM 128
#define CH    204800            // B*H*V*D
#define CH4   (CH / 4)          // 51200 float4 channels
#define VD    (25 * 64)         // V*D
#define DEPTH 8                 // pipeline depth in (kv,q) pairs

typedef float f32x4 __attribute__((ext_vector_type(4)));

__global__ __launch_bounds__(64) void sss_scan_v6(
    const f32x4* __restrict__ q,
    const f32x4* __restrict__ kv,
    const float* __restrict__ decay,
    f32x4* __restrict__ out)
{
    const int i  = blockIdx.x * 64 + threadIdx.x;   // float4-channel index
    const int e0 = i * 4;
    const int dd = e0 & 63;          // d-offset within D=64 (multiple of 4)
    const int h  = (e0 / VD) & 7;    // head index

    const f32x4 d   = *(const f32x4*)(decay + h * 64 + dd);
    const f32x4 omd = 1.0f - d;

    const f32x4* __restrict__ qp = q  + i;
    const f32x4* __restrict__ kp = kv + i;
    f32x4*       __restrict__ op = out + i;

    f32x4 S = (f32x4)0.0f;

    f32x4 kbuf[DEPTH], qbuf[DEPTH];

    // ---- prologue: fill the pipeline (8 pairs = 16 KB/wave in flight) ----
    #pragma unroll
    for (int t = 0; t < DEPTH; ++t) {
        kbuf[t] = kp[(size_t)t * CH4];
        qbuf[t] = qp[(size_t)t * CH4];
    }
    __builtin_amdgcn_sched_barrier(0);

    // ---- steady state, fully unrolled: consume step t, prefetch t+DEPTH ----
    #pragma unroll
    for (int t = 0; t < T_DIM; ++t) {
        const int j = t & (DEPTH - 1);               // compile-time after unroll

        S[0] = fmaf(d[0], S[0], omd[0] * kbuf[j][0]);
        S[1] = fmaf(d[1], S[1], omd[1] * kbuf[j][1]);
        S[2] = fmaf(d[2], S[2], omd[2] * kbuf[j][2]);
        S[3] = fmaf(d[3], S[3], omd[3] * kbuf[j][3]);

        f32x4 o = qbuf[j] * S;
        __builtin_nontemporal_store(o, op + (size_t)t * CH4);

        if (t + DEPTH < T_DIM) {                     // constant-folded per step
            kbuf[j] = kp[(size_t)(t + DEPTH) * CH4];
            qbuf[j] = qp[(size_t)(t + DEPTH) * CH4];
        }
        // Pin the pipeline: nothing (in particular the prefetch loads) may be
        // scheduled across a step boundary. This is what v4 was missing.
        __builtin_amdgcn_sched_barrier(0);
    }
}

extern "C" void kernel_launch(void* const* d_in, const int* in_sizes, int n_in,
                              void* d_out, int out_size, void* d_ws, size_t ws_size,
                              hipStream_t stream) {
    const f32x4* q     = (const f32x4*)d_in[0];
    const f32x4* kv    = (const f32x4*)d_in[1];
    const float* decay = (const float*)d_in[2];
    f32x4* out = (f32x4*)d_out;

    const int threads = 64;
    const int blocks  = CH4 / threads;  // 800 single-wave blocks -> all 256 CUs busy
    sss_scan_v6<<<blocks, threads, 0, stream>>>(q, kv, decay, out);
}